// Round 3
// baseline (6750.268 us; speedup 1.0000x reference)
//
#include <hip/hip_runtime.h>
#include <hip/hip_bf16.h>

#define N_NODES 500000
#define F 128
#define B 20000
#define T 8
#define H1 128
#define H2 64
#define C 32
#define S1 5
#define S2 2
#define BK 16

// ---------------------------------------------------------------------------
// K1: PQ[n] = [ x[n]@w_l0 + b_l0 | x[n]@w_r0 + b_r0 ]   (500000 x 256 fp32)
// BM=64, BN=256, BK=16, 256 threads, 8x8 outputs/thread.
// Register-prefetch pipeline: issue next tile's global loads before computing
// the current LDS tile; ds_write after the post-compute barrier.
// ---------------------------------------------------------------------------
__global__ __launch_bounds__(256, 4) void k1_pq(
    const float* __restrict__ x,
    const float* __restrict__ w_l0, const float* __restrict__ b_l0,
    const float* __restrict__ w_r0, const float* __restrict__ b_r0,
    float* __restrict__ PQ)
{
    __shared__ float At[BK][68];    // [k][row], pad 68 (2-way max on stores)
    __shared__ float Wt[BK][256];   // [k][col]; col<128 = w_l0, else w_r0

    const int tid = threadIdx.x;
    const int tx  = tid & 31;       // col group (8 cols: 4 in P, 4 in Q)
    const int ty  = tid >> 5;       // row group (8 rows)
    const int m0  = blockIdx.x * 64;

    // A staging assignment: 64 rows x 4 float4-chunks = 256 threads
    const int ar  = tid >> 2;       // 0..63
    const int ac4 = tid & 3;        // 0..3

    float4 pa;                      // prefetched A
    float4 pw[4];                   // prefetched W

    auto load_tile = [&](int kk) {
        int row = m0 + ar;
        pa = make_float4(0.f, 0.f, 0.f, 0.f);
        if (row < N_NODES)
            pa = *(const float4*)(x + (size_t)row * F + kk + ac4 * 4);
        #pragma unroll
        for (int i = 0; i < 4; i++) {
            int lin = tid + i * 256;        // 0..1023
            int k   = lin >> 6;             // 0..15
            int c   = (lin & 63) * 4;       // 0..252
            const float* src = (c < 128)
                ? (w_l0 + (size_t)(kk + k) * 128 + c)
                : (w_r0 + (size_t)(kk + k) * 128 + (c - 128));
            pw[i] = *(const float4*)src;
        }
    };
    auto store_tile = [&]() {
        At[ac4 * 4 + 0][ar] = pa.x;
        At[ac4 * 4 + 1][ar] = pa.y;
        At[ac4 * 4 + 2][ar] = pa.z;
        At[ac4 * 4 + 3][ar] = pa.w;
        #pragma unroll
        for (int i = 0; i < 4; i++) {
            int lin = tid + i * 256;
            int k   = lin >> 6;
            int c   = (lin & 63) * 4;
            *(float4*)&Wt[k][c] = pw[i];
        }
    };

    float acc[8][8];
    #pragma unroll
    for (int i = 0; i < 8; i++)
        #pragma unroll
        for (int j = 0; j < 8; j++) acc[i][j] = 0.f;

    load_tile(0);
    store_tile();
    __syncthreads();

    for (int it = 0; it < 128 / BK; it++) {
        if (it < 128 / BK - 1) load_tile((it + 1) * BK);   // issue early
        #pragma unroll
        for (int k = 0; k < BK; k++) {
            float4 a0 = *(const float4*)&At[k][ty * 8];
            float4 a1 = *(const float4*)&At[k][ty * 8 + 4];
            float4 w0 = *(const float4*)&Wt[k][tx * 4];
            float4 w1 = *(const float4*)&Wt[k][128 + tx * 4];
            float a[8] = {a0.x, a0.y, a0.z, a0.w, a1.x, a1.y, a1.z, a1.w};
            float w[8] = {w0.x, w0.y, w0.z, w0.w, w1.x, w1.y, w1.z, w1.w};
            #pragma unroll
            for (int r = 0; r < 8; r++)
                #pragma unroll
                for (int c = 0; c < 8; c++)
                    acc[r][c] += a[r] * w[c];
        }
        __syncthreads();
        if (it < 128 / BK - 1) {
            store_tile();
            __syncthreads();
        }
    }

    float4 bl = *(const float4*)(b_l0 + tx * 4);
    float4 br = *(const float4*)(b_r0 + tx * 4);
    #pragma unroll
    for (int r = 0; r < 8; r++) {
        int row = m0 + ty * 8 + r;
        if (row >= N_NODES) break;
        float4 p = make_float4(acc[r][0] + bl.x, acc[r][1] + bl.y,
                               acc[r][2] + bl.z, acc[r][3] + bl.w);
        float4 q = make_float4(acc[r][4] + br.x, acc[r][5] + br.y,
                               acc[r][6] + br.z, acc[r][7] + br.w);
        *(float4*)(PQ + (size_t)row * 256 + tx * 4)       = p;
        *(float4*)(PQ + (size_t)row * 256 + 128 + tx * 4) = q;
    }
}

// ---------------------------------------------------------------------------
// K2: one wave per (b,t). All 21 row-gathers issued into registers up front,
// then ballots, then sparse weight-row walks with independent accumulators.
// ---------------------------------------------------------------------------
__device__ __forceinline__ void mask_walk(unsigned long long m, int par,
                                          const float* __restrict__ w,
                                          int lane, float& acc)
{
    while (m) {
        int i = __builtin_ctzll(m);
        m &= m - 1;
        acc += w[(size_t)(2 * i + par) * H2 + lane];
    }
}

template <int MODE>
__global__ __launch_bounds__(256) void k2_step(
    const float* __restrict__ x,
    const int* __restrict__ nodes, const int* __restrict__ nbr1,
    const int* __restrict__ nbr2,
    const float* __restrict__ w_l0, const float* __restrict__ b_l0,
    const float* __restrict__ w_r0, const float* __restrict__ b_r0,
    const float* __restrict__ w_l1, const float* __restrict__ b_l1,
    const float* __restrict__ w_r1, const float* __restrict__ b_r1,
    const float* __restrict__ PQ,
    unsigned long long* __restrict__ bits)
{
    const int lane = threadIdx.x & 63;
    const int wv   = threadIdx.x >> 6;
    const int gw   = __builtin_amdgcn_readfirstlane((int)(blockIdx.x * 4 + wv));
    const int b    = gw >> 3;
    const int t    = gw & 7;
    const int c2   = lane * 2;

    if (MODE == 0) {
        const int i_self = nodes[b];
        int i1[S1];
        #pragma unroll
        for (int s = 0; s < S1; s++) i1[s] = nbr1[t * (B * S1) + b * S1 + s];
        int i2[S1 * S2];
        #pragma unroll
        for (int q = 0; q < S1 * S2; q++) i2[q] = nbr2[t * (B * S1 * S2) + b * S1 * S2 + q];

        float2 sp = *(const float2*)(PQ + (size_t)i_self * 256 + c2);
        float2 p1[S1], q1[S1], q2[S1 * S2];
        #pragma unroll
        for (int s = 0; s < S1; s++)
            p1[s] = *(const float2*)(PQ + (size_t)i1[s] * 256 + c2);
        #pragma unroll
        for (int s = 0; s < S1; s++)
            q1[s] = *(const float2*)(PQ + (size_t)i1[s] * 256 + 128 + c2);
        #pragma unroll
        for (int u = 0; u < S1 * S2; u++)
            q2[u] = *(const float2*)(PQ + (size_t)i2[u] * 256 + 128 + c2);

        float qsx = 0.f, qsy = 0.f;
        #pragma unroll
        for (int s = 0; s < S1; s++) { qsx += q1[s].x; qsy += q1[s].y; }
        unsigned long long mLx = __ballot(sp.x + 0.2f * qsx >= 1.0f);
        unsigned long long mLy = __ballot(sp.y + 0.2f * qsy >= 1.0f);
        unsigned long long mRx[S1], mRy[S1];
        #pragma unroll
        for (int r = 0; r < S1; r++) {
            float cx = p1[r].x + 0.5f * (q2[2 * r].x + q2[2 * r + 1].x);
            float cy = p1[r].y + 0.5f * (q2[2 * r].y + q2[2 * r + 1].y);
            mRx[r] = __ballot(cx >= 1.0f);
            mRy[r] = __ballot(cy >= 1.0f);
        }

        float aL0 = 0.f, aL1 = 0.f;
        float aR0 = 0.f, aR1 = 0.f, aR2 = 0.f, aR3 = 0.f;
        mask_walk(mLx, 0, w_l1, lane, aL0);
        mask_walk(mLy, 1, w_l1, lane, aL1);
        mask_walk(mRx[0], 0, w_r1, lane, aR0);
        mask_walk(mRy[0], 1, w_r1, lane, aR1);
        mask_walk(mRx[1], 0, w_r1, lane, aR2);
        mask_walk(mRy[1], 1, w_r1, lane, aR3);
        mask_walk(mRx[2], 0, w_r1, lane, aR0);
        mask_walk(mRy[2], 1, w_r1, lane, aR1);
        mask_walk(mRx[3], 0, w_r1, lane, aR2);
        mask_walk(mRy[3], 1, w_r1, lane, aR3);
        mask_walk(mRx[4], 0, w_r1, lane, aR0);
        mask_walk(mRy[4], 1, w_r1, lane, aR1);

        float cur1 = (aL0 + aL1) + 0.2f * ((aR0 + aR1) + (aR2 + aR3))
                   + b_l1[lane] + b_r1[lane];
        unsigned long long sb = __ballot(cur1 >= 1.0f);
        if (lane == 0) bits[(size_t)b * T + t] = sb;
    } else {
        __shared__ float a_lds[4][F];
        __shared__ float n_lds[4][F];
        const int i_self = nodes[b];
        int i1[S1];
        #pragma unroll
        for (int s = 0; s < S1; s++) i1[s] = nbr1[t * (B * S1) + b * S1 + s];
        int i2[S1 * S2];
        #pragma unroll
        for (int q = 0; q < S1 * S2; q++) i2[q] = nbr2[t * (B * S1 * S2) + b * S1 * S2 + q];

        float accL = 0.f, accR = 0.f;
        const float b0x = b_l0[c2] + b_r0[c2];
        const float b0y = b_l0[c2 + 1] + b_r0[c2 + 1];
        float nsx = 0.f, nsy = 0.f;
        #pragma unroll 1
        for (int r = 1; r < 6; r++) {
            const float* ar = x + (size_t)i1[r - 1] * F;
            float ax = ar[c2], ay = ar[c2 + 1];
            nsx += ax; nsy += ay;
            const float* ch0 = x + (size_t)i2[(r - 1) * 2] * F;
            const float* ch1 = x + (size_t)i2[(r - 1) * 2 + 1] * F;
            float nx = 0.5f * (ch0[c2]     + ch1[c2]);
            float ny = 0.5f * (ch0[c2 + 1] + ch1[c2 + 1]);
            a_lds[wv][c2] = ax; a_lds[wv][c2 + 1] = ay;
            n_lds[wv][c2] = nx; n_lds[wv][c2 + 1] = ny;
            float cx = b0x, cy = b0y;
            #pragma unroll 4
            for (int k = 0; k < F; k++) {
                float ak = a_lds[wv][k], nk = n_lds[wv][k];
                const float* wl = w_l0 + (size_t)k * H1 + c2;
                const float* wr = w_r0 + (size_t)k * H1 + c2;
                cx += ak * wl[0] + nk * wr[0];
                cy += ak * wl[1] + nk * wr[1];
            }
            mask_walk(__ballot(cx >= 1.0f), 0, w_r1, lane, accR);
            mask_walk(__ballot(cy >= 1.0f), 1, w_r1, lane, accR);
        }
        {
            const float* ar = x + (size_t)i_self * F;
            float ax = ar[c2], ay = ar[c2 + 1];
            a_lds[wv][c2] = ax; a_lds[wv][c2 + 1] = ay;
            n_lds[wv][c2] = 0.2f * nsx; n_lds[wv][c2 + 1] = 0.2f * nsy;
            float cx = b0x, cy = b0y;
            #pragma unroll 4
            for (int k = 0; k < F; k++) {
                float ak = a_lds[wv][k], nk = n_lds[wv][k];
                const float* wl = w_l0 + (size_t)k * H1 + c2;
                const float* wr = w_r0 + (size_t)k * H1 + c2;
                cx += ak * wl[0] + nk * wr[0];
                cy += ak * wl[1] + nk * wr[1];
            }
            mask_walk(__ballot(cx >= 1.0f), 0, w_l1, lane, accL);
            mask_walk(__ballot(cy >= 1.0f), 1, w_l1, lane, accL);
        }
        float cur1 = accL + 0.2f * accR + b_l1[lane] + b_r1[lane];
        unsigned long long sb = __ballot(cur1 >= 1.0f);
        if (lane == 0) bits[(size_t)b * T + t] = sb;
    }
}

// ---------------------------------------------------------------------------
// K3: out[b][c] = b_pool[c] + sum over set spike bits of w_pool[(t*64+j)][c]
// ---------------------------------------------------------------------------
__global__ __launch_bounds__(256) void k3_pool(
    const float* __restrict__ w_pool, const float* __restrict__ b_pool,
    const unsigned long long* __restrict__ bits, float* __restrict__ out)
{
    const int tid = threadIdx.x;
    const int c = tid & 31;
    const int g = tid >> 5;
    const int b = blockIdx.x * 8 + g;
    if (b >= B) return;
    float acc = b_pool[c];
    #pragma unroll
    for (int t = 0; t < T; t++) {
        unsigned long long m = bits[(size_t)b * T + t];
        while (m) {
            int j = __builtin_ctzll(m);
            m &= m - 1;
            acc += w_pool[(size_t)(t * H2 + j) * C + c];
        }
    }
    out[(size_t)b * C + c] = acc;
}

extern "C" void kernel_launch(void* const* d_in, const int* in_sizes, int n_in,
                              void* d_out, int out_size, void* d_ws, size_t ws_size,
                              hipStream_t stream)
{
    const float* x      = (const float*)d_in[0];
    const int*   nodes  = (const int*)d_in[1];
    const int*   nbr1   = (const int*)d_in[2];
    const int*   nbr2   = (const int*)d_in[3];
    const float* w_l0   = (const float*)d_in[4];
    const float* b_l0   = (const float*)d_in[5];
    const float* w_r0   = (const float*)d_in[6];
    const float* b_r0   = (const float*)d_in[7];
    const float* w_l1   = (const float*)d_in[8];
    const float* b_l1   = (const float*)d_in[9];
    const float* w_r1   = (const float*)d_in[10];
    const float* b_r1   = (const float*)d_in[11];
    const float* w_pool = (const float*)d_in[12];
    const float* b_pool = (const float*)d_in[13];
    float* out = (float*)d_out;

    const size_t pq_bytes   = (size_t)N_NODES * 256 * sizeof(float);
    const size_t bits_bytes = (size_t)B * T * sizeof(unsigned long long);

    if (ws_size >= pq_bytes + bits_bytes) {
        float* PQ = (float*)d_ws;
        unsigned long long* bits = (unsigned long long*)((char*)d_ws + pq_bytes);
        k1_pq<<<(N_NODES + 63) / 64, 256, 0, stream>>>(x, w_l0, b_l0, w_r0, b_r0, PQ);
        k2_step<0><<<(B * T) / 4, 256, 0, stream>>>(x, nodes, nbr1, nbr2,
            w_l0, b_l0, w_r0, b_r0, w_l1, b_l1, w_r1, b_r1, PQ, bits);
        k3_pool<<<B / 8, 256, 0, stream>>>(w_pool, b_pool, bits, out);
    } else {
        unsigned long long* bits = (unsigned long long*)d_ws;
        k2_step<1><<<(B * T) / 4, 256, 0, stream>>>(x, nodes, nbr1, nbr2,
            w_l0, b_l0, w_r0, b_r0, w_l1, b_l1, w_r1, b_r1, nullptr, bits);
        k3_pool<<<B / 8, 256, 0, stream>>>(w_pool, b_pool, bits, out);
    }
}

// Round 4
// 2712.996 us; speedup vs baseline: 2.4881x; 2.4881x over previous
//
#include <hip/hip_runtime.h>
#include <hip/hip_bf16.h>

#define N_NODES 500000
#define F 128
#define B 20000
#define T 8
#define H1 128
#define H2 64
#define C 32
#define S1 5
#define S2 2
#define BK 16

// ---------------------------------------------------------------------------
// K1: PQ[n] = [ x[n]@w_l0 + b_l0 | x[n]@w_r0 + b_r0 ]   (500000 x 256 fp32)
// BM=64, BN=256, BK=16, 256 threads, 8x8 outputs/thread.
// Double-buffered LDS, one barrier/iter. Prefetch for tile it+1 is issued
// before computing tile it; ds_writes (dependent only on the loads) sink
// after the compute phase. Named prefetch regs — no arrays, no lambdas
// (R3 lesson: lambda-captured arrays + tight launch_bounds spilled acc[8][8]
// to scratch -> 17.8 GB of scratch writes).
// ---------------------------------------------------------------------------
__global__ __launch_bounds__(256, 2) void k1_pq(
    const float* __restrict__ x,
    const float* __restrict__ w_l0, const float* __restrict__ b_l0,
    const float* __restrict__ w_r0, const float* __restrict__ b_r0,
    float* __restrict__ PQ)
{
    __shared__ float At[2][BK][68];     // [buf][k][row], padded
    __shared__ float Wt[2][BK][256];    // [buf][k][col]; col<128=w_l0 else w_r0

    const int tid = threadIdx.x;
    const int tx  = tid & 31;           // col group (4 cols in P + 4 in Q)
    const int ty  = tid >> 5;           // row group (8 rows)
    const int m0  = blockIdx.x * 64;

    // A staging: 64 rows x 4 float4 chunks = 256 threads (1 float4 each)
    const int ar   = tid >> 2;          // 0..63
    const int ac4  = tid & 3;           // 0..3
    const int arow = m0 + ar;
    const float* asrc = x + (size_t)arow * F + ac4 * 4;   // + kk

    // W staging: 4 float4/thread; k = wk0 + {0,4,8,12}, col fixed
    const int wk0 = tid >> 6;           // 0..3
    const int wc0 = (tid & 63) * 4;     // 0..252
    const float* wsrc = (wc0 < 128) ? (w_l0 + wc0) : (w_r0 + (wc0 - 128));

    float4 pa, pw0, pw1, pw2, pw3;

    // ---- prologue: stage tile 0 into buf 0 ----
    pa = make_float4(0.f, 0.f, 0.f, 0.f);
    if (arow < N_NODES) pa = *(const float4*)(asrc);
    pw0 = *(const float4*)(wsrc + (size_t)(wk0 +  0) * 128);
    pw1 = *(const float4*)(wsrc + (size_t)(wk0 +  4) * 128);
    pw2 = *(const float4*)(wsrc + (size_t)(wk0 +  8) * 128);
    pw3 = *(const float4*)(wsrc + (size_t)(wk0 + 12) * 128);
    At[0][ac4 * 4 + 0][ar] = pa.x;
    At[0][ac4 * 4 + 1][ar] = pa.y;
    At[0][ac4 * 4 + 2][ar] = pa.z;
    At[0][ac4 * 4 + 3][ar] = pa.w;
    *(float4*)&Wt[0][wk0 +  0][wc0] = pw0;
    *(float4*)&Wt[0][wk0 +  4][wc0] = pw1;
    *(float4*)&Wt[0][wk0 +  8][wc0] = pw2;
    *(float4*)&Wt[0][wk0 + 12][wc0] = pw3;
    __syncthreads();

    float acc[8][8];
    #pragma unroll
    for (int i = 0; i < 8; i++)
        #pragma unroll
        for (int j = 0; j < 8; j++) acc[i][j] = 0.f;

    for (int it = 0; it < F / BK; ++it) {
        const int cur = it & 1;
        const int nxt = cur ^ 1;
        const int kk1 = (it + 1) * BK;
        const bool more = (it < F / BK - 1);

        if (more) {   // issue next tile's global loads early
            pa = make_float4(0.f, 0.f, 0.f, 0.f);
            if (arow < N_NODES) pa = *(const float4*)(asrc + kk1);
            pw0 = *(const float4*)(wsrc + (size_t)(kk1 + wk0 +  0) * 128);
            pw1 = *(const float4*)(wsrc + (size_t)(kk1 + wk0 +  4) * 128);
            pw2 = *(const float4*)(wsrc + (size_t)(kk1 + wk0 +  8) * 128);
            pw3 = *(const float4*)(wsrc + (size_t)(kk1 + wk0 + 12) * 128);
        }

        #pragma unroll
        for (int k = 0; k < BK; ++k) {
            float4 a0 = *(const float4*)&At[cur][k][ty * 8];
            float4 a1 = *(const float4*)&At[cur][k][ty * 8 + 4];
            float4 w0 = *(const float4*)&Wt[cur][k][tx * 4];
            float4 w1 = *(const float4*)&Wt[cur][k][128 + tx * 4];
            float a[8] = {a0.x, a0.y, a0.z, a0.w, a1.x, a1.y, a1.z, a1.w};
            float w[8] = {w0.x, w0.y, w0.z, w0.w, w1.x, w1.y, w1.z, w1.w};
            #pragma unroll
            for (int r = 0; r < 8; r++)
                #pragma unroll
                for (int c = 0; c < 8; c++)
                    acc[r][c] += a[r] * w[c];
        }

        if (more) {   // write prefetched tile to the other buffer
            At[nxt][ac4 * 4 + 0][ar] = pa.x;
            At[nxt][ac4 * 4 + 1][ar] = pa.y;
            At[nxt][ac4 * 4 + 2][ar] = pa.z;
            At[nxt][ac4 * 4 + 3][ar] = pa.w;
            *(float4*)&Wt[nxt][wk0 +  0][wc0] = pw0;
            *(float4*)&Wt[nxt][wk0 +  4][wc0] = pw1;
            *(float4*)&Wt[nxt][wk0 +  8][wc0] = pw2;
            *(float4*)&Wt[nxt][wk0 + 12][wc0] = pw3;
        }
        __syncthreads();
    }

    float4 bl = *(const float4*)(b_l0 + tx * 4);
    float4 br = *(const float4*)(b_r0 + tx * 4);
    #pragma unroll
    for (int r = 0; r < 8; r++) {
        int row = m0 + ty * 8 + r;
        if (row >= N_NODES) break;
        float4 p = make_float4(acc[r][0] + bl.x, acc[r][1] + bl.y,
                               acc[r][2] + bl.z, acc[r][3] + bl.w);
        float4 q = make_float4(acc[r][4] + br.x, acc[r][5] + br.y,
                               acc[r][6] + br.z, acc[r][7] + br.w);
        *(float4*)(PQ + (size_t)row * 256 + tx * 4)       = p;
        *(float4*)(PQ + (size_t)row * 256 + 128 + tx * 4) = q;
    }
}

// ---------------------------------------------------------------------------
// K2: one wave per (b,t). All 21 row-gathers issued into registers up front,
// then ballots, then sparse weight-row walks with independent accumulators.
// ---------------------------------------------------------------------------
__device__ __forceinline__ void mask_walk(unsigned long long m, int par,
                                          const float* __restrict__ w,
                                          int lane, float& acc)
{
    while (m) {
        int i = __builtin_ctzll(m);
        m &= m - 1;
        acc += w[(size_t)(2 * i + par) * H2 + lane];
    }
}

template <int MODE>
__global__ __launch_bounds__(256) void k2_step(
    const float* __restrict__ x,
    const int* __restrict__ nodes, const int* __restrict__ nbr1,
    const int* __restrict__ nbr2,
    const float* __restrict__ w_l0, const float* __restrict__ b_l0,
    const float* __restrict__ w_r0, const float* __restrict__ b_r0,
    const float* __restrict__ w_l1, const float* __restrict__ b_l1,
    const float* __restrict__ w_r1, const float* __restrict__ b_r1,
    const float* __restrict__ PQ,
    unsigned long long* __restrict__ bits)
{
    const int lane = threadIdx.x & 63;
    const int wv   = threadIdx.x >> 6;
    const int gw   = __builtin_amdgcn_readfirstlane((int)(blockIdx.x * 4 + wv));
    const int b    = gw >> 3;
    const int t    = gw & 7;
    const int c2   = lane * 2;

    if (MODE == 0) {
        const int i_self = nodes[b];
        int i1[S1];
        #pragma unroll
        for (int s = 0; s < S1; s++) i1[s] = nbr1[t * (B * S1) + b * S1 + s];
        int i2[S1 * S2];
        #pragma unroll
        for (int q = 0; q < S1 * S2; q++) i2[q] = nbr2[t * (B * S1 * S2) + b * S1 * S2 + q];

        float2 sp = *(const float2*)(PQ + (size_t)i_self * 256 + c2);
        float2 p1[S1], q1[S1], q2[S1 * S2];
        #pragma unroll
        for (int s = 0; s < S1; s++)
            p1[s] = *(const float2*)(PQ + (size_t)i1[s] * 256 + c2);
        #pragma unroll
        for (int s = 0; s < S1; s++)
            q1[s] = *(const float2*)(PQ + (size_t)i1[s] * 256 + 128 + c2);
        #pragma unroll
        for (int u = 0; u < S1 * S2; u++)
            q2[u] = *(const float2*)(PQ + (size_t)i2[u] * 256 + 128 + c2);

        float qsx = 0.f, qsy = 0.f;
        #pragma unroll
        for (int s = 0; s < S1; s++) { qsx += q1[s].x; qsy += q1[s].y; }
        unsigned long long mLx = __ballot(sp.x + 0.2f * qsx >= 1.0f);
        unsigned long long mLy = __ballot(sp.y + 0.2f * qsy >= 1.0f);
        unsigned long long mRx[S1], mRy[S1];
        #pragma unroll
        for (int r = 0; r < S1; r++) {
            float cx = p1[r].x + 0.5f * (q2[2 * r].x + q2[2 * r + 1].x);
            float cy = p1[r].y + 0.5f * (q2[2 * r].y + q2[2 * r + 1].y);
            mRx[r] = __ballot(cx >= 1.0f);
            mRy[r] = __ballot(cy >= 1.0f);
        }

        float aL0 = 0.f, aL1 = 0.f;
        float aR0 = 0.f, aR1 = 0.f, aR2 = 0.f, aR3 = 0.f;
        mask_walk(mLx, 0, w_l1, lane, aL0);
        mask_walk(mLy, 1, w_l1, lane, aL1);
        mask_walk(mRx[0], 0, w_r1, lane, aR0);
        mask_walk(mRy[0], 1, w_r1, lane, aR1);
        mask_walk(mRx[1], 0, w_r1, lane, aR2);
        mask_walk(mRy[1], 1, w_r1, lane, aR3);
        mask_walk(mRx[2], 0, w_r1, lane, aR0);
        mask_walk(mRy[2], 1, w_r1, lane, aR1);
        mask_walk(mRx[3], 0, w_r1, lane, aR2);
        mask_walk(mRy[3], 1, w_r1, lane, aR3);
        mask_walk(mRx[4], 0, w_r1, lane, aR0);
        mask_walk(mRy[4], 1, w_r1, lane, aR1);

        float cur1 = (aL0 + aL1) + 0.2f * ((aR0 + aR1) + (aR2 + aR3))
                   + b_l1[lane] + b_r1[lane];
        unsigned long long sb = __ballot(cur1 >= 1.0f);
        if (lane == 0) bits[(size_t)b * T + t] = sb;
    } else {
        __shared__ float a_lds[4][F];
        __shared__ float n_lds[4][F];
        const int i_self = nodes[b];
        int i1[S1];
        #pragma unroll
        for (int s = 0; s < S1; s++) i1[s] = nbr1[t * (B * S1) + b * S1 + s];
        int i2[S1 * S2];
        #pragma unroll
        for (int q = 0; q < S1 * S2; q++) i2[q] = nbr2[t * (B * S1 * S2) + b * S1 * S2 + q];

        float accL = 0.f, accR = 0.f;
        const float b0x = b_l0[c2] + b_r0[c2];
        const float b0y = b_l0[c2 + 1] + b_r0[c2 + 1];
        float nsx = 0.f, nsy = 0.f;
        #pragma unroll 1
        for (int r = 1; r < 6; r++) {
            const float* ar = x + (size_t)i1[r - 1] * F;
            float ax = ar[c2], ay = ar[c2 + 1];
            nsx += ax; nsy += ay;
            const float* ch0 = x + (size_t)i2[(r - 1) * 2] * F;
            const float* ch1 = x + (size_t)i2[(r - 1) * 2 + 1] * F;
            float nx = 0.5f * (ch0[c2]     + ch1[c2]);
            float ny = 0.5f * (ch0[c2 + 1] + ch1[c2 + 1]);
            a_lds[wv][c2] = ax; a_lds[wv][c2 + 1] = ay;
            n_lds[wv][c2] = nx; n_lds[wv][c2 + 1] = ny;
            float cx = b0x, cy = b0y;
            #pragma unroll 4
            for (int k = 0; k < F; k++) {
                float ak = a_lds[wv][k], nk = n_lds[wv][k];
                const float* wl = w_l0 + (size_t)k * H1 + c2;
                const float* wr = w_r0 + (size_t)k * H1 + c2;
                cx += ak * wl[0] + nk * wr[0];
                cy += ak * wl[1] + nk * wr[1];
            }
            mask_walk(__ballot(cx >= 1.0f), 0, w_r1, lane, accR);
            mask_walk(__ballot(cy >= 1.0f), 1, w_r1, lane, accR);
        }
        {
            const float* ar = x + (size_t)i_self * F;
            float ax = ar[c2], ay = ar[c2 + 1];
            a_lds[wv][c2] = ax; a_lds[wv][c2 + 1] = ay;
            n_lds[wv][c2] = 0.2f * nsx; n_lds[wv][c2 + 1] = 0.2f * nsy;
            float cx = b0x, cy = b0y;
            #pragma unroll 4
            for (int k = 0; k < F; k++) {
                float ak = a_lds[wv][k], nk = n_lds[wv][k];
                const float* wl = w_l0 + (size_t)k * H1 + c2;
                const float* wr = w_r0 + (size_t)k * H1 + c2;
                cx += ak * wl[0] + nk * wr[0];
                cy += ak * wl[1] + nk * wr[1];
            }
            mask_walk(__ballot(cx >= 1.0f), 0, w_l1, lane, accL);
            mask_walk(__ballot(cy >= 1.0f), 1, w_l1, lane, accL);
        }
        float cur1 = accL + 0.2f * accR + b_l1[lane] + b_r1[lane];
        unsigned long long sb = __ballot(cur1 >= 1.0f);
        if (lane == 0) bits[(size_t)b * T + t] = sb;
    }
}

// ---------------------------------------------------------------------------
// K3: out[b][c] = b_pool[c] + sum over set spike bits of w_pool[(t*64+j)][c]
// ---------------------------------------------------------------------------
__global__ __launch_bounds__(256) void k3_pool(
    const float* __restrict__ w_pool, const float* __restrict__ b_pool,
    const unsigned long long* __restrict__ bits, float* __restrict__ out)
{
    const int tid = threadIdx.x;
    const int c = tid & 31;
    const int g = tid >> 5;
    const int b = blockIdx.x * 8 + g;
    if (b >= B) return;
    float acc = b_pool[c];
    #pragma unroll
    for (int t = 0; t < T; t++) {
        unsigned long long m = bits[(size_t)b * T + t];
        while (m) {
            int j = __builtin_ctzll(m);
            m &= m - 1;
            acc += w_pool[(size_t)(t * H2 + j) * C + c];
        }
    }
    out[(size_t)b * C + c] = acc;
}

extern "C" void kernel_launch(void* const* d_in, const int* in_sizes, int n_in,
                              void* d_out, int out_size, void* d_ws, size_t ws_size,
                              hipStream_t stream)
{
    const float* x      = (const float*)d_in[0];
    const int*   nodes  = (const int*)d_in[1];
    const int*   nbr1   = (const int*)d_in[2];
    const int*   nbr2   = (const int*)d_in[3];
    const float* w_l0   = (const float*)d_in[4];
    const float* b_l0   = (const float*)d_in[5];
    const float* w_r0   = (const float*)d_in[6];
    const float* b_r0   = (const float*)d_in[7];
    const float* w_l1   = (const float*)d_in[8];
    const float* b_l1   = (const float*)d_in[9];
    const float* w_r1   = (const float*)d_in[10];
    const float* b_r1   = (const float*)d_in[11];
    const float* w_pool = (const float*)d_in[12];
    const float* b_pool = (const float*)d_in[13];
    float* out = (float*)d_out;

    const size_t pq_bytes   = (size_t)N_NODES * 256 * sizeof(float);
    const size_t bits_bytes = (size_t)B * T * sizeof(unsigned long long);

    if (ws_size >= pq_bytes + bits_bytes) {
        float* PQ = (float*)d_ws;
        unsigned long long* bits = (unsigned long long*)((char*)d_ws + pq_bytes);
        k1_pq<<<(N_NODES + 63) / 64, 256, 0, stream>>>(x, w_l0, b_l0, w_r0, b_r0, PQ);
        k2_step<0><<<(B * T) / 4, 256, 0, stream>>>(x, nodes, nbr1, nbr2,
            w_l0, b_l0, w_r0, b_r0, w_l1, b_l1, w_r1, b_r1, PQ, bits);
        k3_pool<<<B / 8, 256, 0, stream>>>(w_pool, b_pool, bits, out);
    } else {
        unsigned long long* bits = (unsigned long long*)d_ws;
        k2_step<1><<<(B * T) / 4, 256, 0, stream>>>(x, nodes, nbr1, nbr2,
            w_l0, b_l0, w_r0, b_r0, w_l1, b_l1, w_r1, b_r1, nullptr, bits);
        k3_pool<<<B / 8, 256, 0, stream>>>(w_pool, b_pool, bits, out);
    }
}

// Round 5
// 738.098 us; speedup vs baseline: 9.1455x; 3.6757x over previous
//
#include <hip/hip_runtime.h>
#include <hip/hip_bf16.h>
#include <stdint.h>

#define N_NODES 500000
#define F 128
#define B 20000
#define T 8
#define H1 128
#define H2 64
#define C 32
#define S1 5
#define S2 2
#define BK 16

// async 16B global -> LDS (direct-to-shared DMA, no VGPR round trip).
// LDS dest is wave-uniform base + lane*16; global src is per-lane.
__device__ __forceinline__ void async_cp16(const float* g, float* l) {
    __builtin_amdgcn_global_load_lds(
        (const __attribute__((address_space(1))) uint32_t*)g,
        (__attribute__((address_space(3))) uint32_t*)l,
        16, 0, 0);
}

// ---------------------------------------------------------------------------
// K1: PQ[n] = [ x[n]@w_l0 + b_l0 | x[n]@w_r0 + b_r0 ]   (500000 x 256 fp32)
// BM=64, BN=256, BK=16, 256 threads, 8x8 outputs/thread.
// Double-buffered LDS staged via global_load_lds (zero staging VGPRs --
// R3/R4 lesson: register-prefetch pipelines spilled acc[8][8] to scratch).
// A stored row-major [row][k] (lane-linear, as global_load_lds requires);
// read via 2-address broadcast ds_read_b64 (2-way conflict = free).
// Plain __launch_bounds__(256): min-waves hints caused the spills.
// ---------------------------------------------------------------------------
__global__ __launch_bounds__(256) void k1_pq(
    const float* __restrict__ x,
    const float* __restrict__ w_l0, const float* __restrict__ b_l0,
    const float* __restrict__ w_r0, const float* __restrict__ b_r0,
    float* __restrict__ PQ)
{
    __shared__ float Ar[2][64][16];     // [buf][row][k]  4KB each
    __shared__ float Wt[2][BK][256];    // [buf][k][col]  16KB each; col<128=w_l0

    const int tid  = threadIdx.x;
    const int tx   = tid & 31;          // col group (4 cols in P + 4 in Q)
    const int ty   = tid >> 5;          // row group (8 rows)
    const int m0   = blockIdx.x * 64;
    const int wv   = tid >> 6;          // wave id 0..3
    const int lane = tid & 63;

    float acc[8][8];
    #pragma unroll
    for (int i = 0; i < 8; i++)
        #pragma unroll
        for (int j = 0; j < 8; j++) acc[i][j] = 0.f;

    // W staging source: per-lane column, fixed; row (k) varies per tile
    const int wc = lane * 4;
    const float* wbase = (wc < 128) ? (w_l0 + wc) : (w_r0 + (wc - 128));

    if (m0 + 64 <= N_NODES) {
        // ---------------- full block: async double-buffered pipeline -------
        // A staging: wave wv covers rows wv*16..wv*16+15 with one instr
        const float* ag = x + (size_t)(m0 + wv * 16 + (lane >> 2)) * F
                            + (lane & 3) * 4;

        // prologue: stage tile 0 into buf 0
        async_cp16(ag, &Ar[0][wv * 16][0]);
        #pragma unroll
        for (int i = 0; i < 4; ++i)
            async_cp16(wbase + (size_t)(wv * 4 + i) * 128, &Wt[0][wv * 4 + i][0]);
        __syncthreads();

        for (int it = 0; it < F / BK; ++it) {
            const int cur = it & 1;
            if (it < F / BK - 1) {      // issue next tile early (async)
                const int kk1 = (it + 1) * BK;
                async_cp16(ag + kk1, &Ar[cur ^ 1][wv * 16][0]);
                #pragma unroll
                for (int i = 0; i < 4; ++i)
                    async_cp16(wbase + (size_t)(kk1 + wv * 4 + i) * 128,
                               &Wt[cur ^ 1][wv * 4 + i][0]);
            }
            #pragma unroll
            for (int k2 = 0; k2 < BK / 2; ++k2) {
                float2 a2[8];
                #pragma unroll
                for (int r = 0; r < 8; ++r)
                    a2[r] = *(const float2*)&Ar[cur][ty * 8 + r][k2 * 2];
                #pragma unroll
                for (int kk2 = 0; kk2 < 2; ++kk2) {
                    const int k = k2 * 2 + kk2;
                    float4 w0 = *(const float4*)&Wt[cur][k][tx * 4];
                    float4 w1 = *(const float4*)&Wt[cur][k][128 + tx * 4];
                    float w[8] = {w0.x, w0.y, w0.z, w0.w,
                                  w1.x, w1.y, w1.z, w1.w};
                    #pragma unroll
                    for (int r = 0; r < 8; ++r) {
                        float av = kk2 ? a2[r].y : a2[r].x;
                        #pragma unroll
                        for (int c = 0; c < 8; ++c) acc[r][c] += av * w[c];
                    }
                }
            }
            __syncthreads();            // drains async loads + orders buffers
        }
    } else {
        // ---------------- tail block (rows 499968..499999): checked path ---
        const int arow = m0 + (tid >> 2);
        const int ac4  = tid & 3;
        for (int it = 0; it < F / BK; ++it) {
            const int kk = it * BK;
            float4 v = make_float4(0.f, 0.f, 0.f, 0.f);
            if (arow < N_NODES)
                v = *(const float4*)(x + (size_t)arow * F + kk + ac4 * 4);
            *(float4*)&Ar[0][tid >> 2][ac4 * 4] = v;
            #pragma unroll
            for (int i = 0; i < 4; ++i) {
                float4 wv4 = *(const float4*)(wbase + (size_t)(kk + wv * 4 + i) * 128);
                *(float4*)&Wt[0][wv * 4 + i][wc] = wv4;
            }
            __syncthreads();
            #pragma unroll
            for (int k2 = 0; k2 < BK / 2; ++k2) {
                float2 a2[8];
                #pragma unroll
                for (int r = 0; r < 8; ++r)
                    a2[r] = *(const float2*)&Ar[0][ty * 8 + r][k2 * 2];
                #pragma unroll
                for (int kk2 = 0; kk2 < 2; ++kk2) {
                    const int k = k2 * 2 + kk2;
                    float4 w0 = *(const float4*)&Wt[0][k][tx * 4];
                    float4 w1 = *(const float4*)&Wt[0][k][128 + tx * 4];
                    float w[8] = {w0.x, w0.y, w0.z, w0.w,
                                  w1.x, w1.y, w1.z, w1.w};
                    #pragma unroll
                    for (int r = 0; r < 8; ++r) {
                        float av = kk2 ? a2[r].y : a2[r].x;
                        #pragma unroll
                        for (int c = 0; c < 8; ++c) acc[r][c] += av * w[c];
                    }
                }
            }
            __syncthreads();
        }
    }

    float4 bl = *(const float4*)(b_l0 + tx * 4);
    float4 br = *(const float4*)(b_r0 + tx * 4);
    #pragma unroll
    for (int r = 0; r < 8; r++) {
        int row = m0 + ty * 8 + r;
        if (row >= N_NODES) break;
        float4 p = make_float4(acc[r][0] + bl.x, acc[r][1] + bl.y,
                               acc[r][2] + bl.z, acc[r][3] + bl.w);
        float4 q = make_float4(acc[r][4] + br.x, acc[r][5] + br.y,
                               acc[r][6] + br.z, acc[r][7] + br.w);
        *(float4*)(PQ + (size_t)row * 256 + tx * 4)       = p;
        *(float4*)(PQ + (size_t)row * 256 + 128 + tx * 4) = q;
    }
}

// ---------------------------------------------------------------------------
// K2: one wave per (b,t). All 21 row-gathers issued into registers up front,
// then ballots, then sparse weight-row walks with independent accumulators.
// ---------------------------------------------------------------------------
__device__ __forceinline__ void mask_walk(unsigned long long m, int par,
                                          const float* __restrict__ w,
                                          int lane, float& acc)
{
    while (m) {
        int i = __builtin_ctzll(m);
        m &= m - 1;
        acc += w[(size_t)(2 * i + par) * H2 + lane];
    }
}

template <int MODE>
__global__ __launch_bounds__(256) void k2_step(
    const float* __restrict__ x,
    const int* __restrict__ nodes, const int* __restrict__ nbr1,
    const int* __restrict__ nbr2,
    const float* __restrict__ w_l0, const float* __restrict__ b_l0,
    const float* __restrict__ w_r0, const float* __restrict__ b_r0,
    const float* __restrict__ w_l1, const float* __restrict__ b_l1,
    const float* __restrict__ w_r1, const float* __restrict__ b_r1,
    const float* __restrict__ PQ,
    unsigned long long* __restrict__ bits)
{
    const int lane = threadIdx.x & 63;
    const int wv   = threadIdx.x >> 6;
    const int gw   = __builtin_amdgcn_readfirstlane((int)(blockIdx.x * 4 + wv));
    const int b    = gw >> 3;
    const int t    = gw & 7;
    const int c2   = lane * 2;

    if (MODE == 0) {
        const int i_self = nodes[b];
        int i1[S1];
        #pragma unroll
        for (int s = 0; s < S1; s++) i1[s] = nbr1[t * (B * S1) + b * S1 + s];
        int i2[S1 * S2];
        #pragma unroll
        for (int q = 0; q < S1 * S2; q++) i2[q] = nbr2[t * (B * S1 * S2) + b * S1 * S2 + q];

        float2 sp = *(const float2*)(PQ + (size_t)i_self * 256 + c2);
        float2 p1[S1], q1[S1], q2[S1 * S2];
        #pragma unroll
        for (int s = 0; s < S1; s++)
            p1[s] = *(const float2*)(PQ + (size_t)i1[s] * 256 + c2);
        #pragma unroll
        for (int s = 0; s < S1; s++)
            q1[s] = *(const float2*)(PQ + (size_t)i1[s] * 256 + 128 + c2);
        #pragma unroll
        for (int u = 0; u < S1 * S2; u++)
            q2[u] = *(const float2*)(PQ + (size_t)i2[u] * 256 + 128 + c2);

        float qsx = 0.f, qsy = 0.f;
        #pragma unroll
        for (int s = 0; s < S1; s++) { qsx += q1[s].x; qsy += q1[s].y; }
        unsigned long long mLx = __ballot(sp.x + 0.2f * qsx >= 1.0f);
        unsigned long long mLy = __ballot(sp.y + 0.2f * qsy >= 1.0f);
        unsigned long long mRx[S1], mRy[S1];
        #pragma unroll
        for (int r = 0; r < S1; r++) {
            float cx = p1[r].x + 0.5f * (q2[2 * r].x + q2[2 * r + 1].x);
            float cy = p1[r].y + 0.5f * (q2[2 * r].y + q2[2 * r + 1].y);
            mRx[r] = __ballot(cx >= 1.0f);
            mRy[r] = __ballot(cy >= 1.0f);
        }

        float aL0 = 0.f, aL1 = 0.f;
        float aR0 = 0.f, aR1 = 0.f, aR2 = 0.f, aR3 = 0.f;
        mask_walk(mLx, 0, w_l1, lane, aL0);
        mask_walk(mLy, 1, w_l1, lane, aL1);
        mask_walk(mRx[0], 0, w_r1, lane, aR0);
        mask_walk(mRy[0], 1, w_r1, lane, aR1);
        mask_walk(mRx[1], 0, w_r1, lane, aR2);
        mask_walk(mRy[1], 1, w_r1, lane, aR3);
        mask_walk(mRx[2], 0, w_r1, lane, aR0);
        mask_walk(mRy[2], 1, w_r1, lane, aR1);
        mask_walk(mRx[3], 0, w_r1, lane, aR2);
        mask_walk(mRy[3], 1, w_r1, lane, aR3);
        mask_walk(mRx[4], 0, w_r1, lane, aR0);
        mask_walk(mRy[4], 1, w_r1, lane, aR1);

        float cur1 = (aL0 + aL1) + 0.2f * ((aR0 + aR1) + (aR2 + aR3))
                   + b_l1[lane] + b_r1[lane];
        unsigned long long sb = __ballot(cur1 >= 1.0f);
        if (lane == 0) bits[(size_t)b * T + t] = sb;
    } else {
        __shared__ float a_lds[4][F];
        __shared__ float n_lds[4][F];
        const int i_self = nodes[b];
        int i1[S1];
        #pragma unroll
        for (int s = 0; s < S1; s++) i1[s] = nbr1[t * (B * S1) + b * S1 + s];
        int i2[S1 * S2];
        #pragma unroll
        for (int q = 0; q < S1 * S2; q++) i2[q] = nbr2[t * (B * S1 * S2) + b * S1 * S2 + q];

        float accL = 0.f, accR = 0.f;
        const float b0x = b_l0[c2] + b_r0[c2];
        const float b0y = b_l0[c2 + 1] + b_r0[c2 + 1];
        float nsx = 0.f, nsy = 0.f;
        #pragma unroll 1
        for (int r = 1; r < 6; r++) {
            const float* ar = x + (size_t)i1[r - 1] * F;
            float ax = ar[c2], ay = ar[c2 + 1];
            nsx += ax; nsy += ay;
            const float* ch0 = x + (size_t)i2[(r - 1) * 2] * F;
            const float* ch1 = x + (size_t)i2[(r - 1) * 2 + 1] * F;
            float nx = 0.5f * (ch0[c2]     + ch1[c2]);
            float ny = 0.5f * (ch0[c2 + 1] + ch1[c2 + 1]);
            a_lds[wv][c2] = ax; a_lds[wv][c2 + 1] = ay;
            n_lds[wv][c2] = nx; n_lds[wv][c2 + 1] = ny;
            float cx = b0x, cy = b0y;
            #pragma unroll 4
            for (int k = 0; k < F; k++) {
                float ak = a_lds[wv][k], nk = n_lds[wv][k];
                const float* wl = w_l0 + (size_t)k * H1 + c2;
                const float* wr = w_r0 + (size_t)k * H1 + c2;
                cx += ak * wl[0] + nk * wr[0];
                cy += ak * wl[1] + nk * wr[1];
            }
            mask_walk(__ballot(cx >= 1.0f), 0, w_r1, lane, accR);
            mask_walk(__ballot(cy >= 1.0f), 1, w_r1, lane, accR);
        }
        {
            const float* ar = x + (size_t)i_self * F;
            float ax = ar[c2], ay = ar[c2 + 1];
            a_lds[wv][c2] = ax; a_lds[wv][c2 + 1] = ay;
            n_lds[wv][c2] = 0.2f * nsx; n_lds[wv][c2 + 1] = 0.2f * nsy;
            float cx = b0x, cy = b0y;
            #pragma unroll 4
            for (int k = 0; k < F; k++) {
                float ak = a_lds[wv][k], nk = n_lds[wv][k];
                const float* wl = w_l0 + (size_t)k * H1 + c2;
                const float* wr = w_r0 + (size_t)k * H1 + c2;
                cx += ak * wl[0] + nk * wr[0];
                cy += ak * wl[1] + nk * wr[1];
            }
            mask_walk(__ballot(cx >= 1.0f), 0, w_l1, lane, accL);
            mask_walk(__ballot(cy >= 1.0f), 1, w_l1, lane, accL);
        }
        float cur1 = accL + 0.2f * accR + b_l1[lane] + b_r1[lane];
        unsigned long long sb = __ballot(cur1 >= 1.0f);
        if (lane == 0) bits[(size_t)b * T + t] = sb;
    }
}

// ---------------------------------------------------------------------------
// K3: out[b][c] = b_pool[c] + sum over set spike bits of w_pool[(t*64+j)][c]
// ---------------------------------------------------------------------------
__global__ __launch_bounds__(256) void k3_pool(
    const float* __restrict__ w_pool, const float* __restrict__ b_pool,
    const unsigned long long* __restrict__ bits, float* __restrict__ out)
{
    const int tid = threadIdx.x;
    const int c = tid & 31;
    const int g = tid >> 5;
    const int b = blockIdx.x * 8 + g;
    if (b >= B) return;
    float acc = b_pool[c];
    #pragma unroll
    for (int t = 0; t < T; t++) {
        unsigned long long m = bits[(size_t)b * T + t];
        while (m) {
            int j = __builtin_ctzll(m);
            m &= m - 1;
            acc += w_pool[(size_t)(t * H2 + j) * C + c];
        }
    }
    out[(size_t)b * C + c] = acc;
}

extern "C" void kernel_launch(void* const* d_in, const int* in_sizes, int n_in,
                              void* d_out, int out_size, void* d_ws, size_t ws_size,
                              hipStream_t stream)
{
    const float* x      = (const float*)d_in[0];
    const int*   nodes  = (const int*)d_in[1];
    const int*   nbr1   = (const int*)d_in[2];
    const int*   nbr2   = (const int*)d_in[3];
    const float* w_l0   = (const float*)d_in[4];
    const float* b_l0   = (const float*)d_in[5];
    const float* w_r0   = (const float*)d_in[6];
    const float* b_r0   = (const float*)d_in[7];
    const float* w_l1   = (const float*)d_in[8];
    const float* b_l1   = (const float*)d_in[9];
    const float* w_r1   = (const float*)d_in[10];
    const float* b_r1   = (const float*)d_in[11];
    const float* w_pool = (const float*)d_in[12];
    const float* b_pool = (const float*)d_in[13];
    float* out = (float*)d_out;

    const size_t pq_bytes   = (size_t)N_NODES * 256 * sizeof(float);
    const size_t bits_bytes = (size_t)B * T * sizeof(unsigned long long);

    if (ws_size >= pq_bytes + bits_bytes) {
        float* PQ = (float*)d_ws;
        unsigned long long* bits = (unsigned long long*)((char*)d_ws + pq_bytes);
        k1_pq<<<(N_NODES + 63) / 64, 256, 0, stream>>>(x, w_l0, b_l0, w_r0, b_r0, PQ);
        k2_step<0><<<(B * T) / 4, 256, 0, stream>>>(x, nodes, nbr1, nbr2,
            w_l0, b_l0, w_r0, b_r0, w_l1, b_l1, w_r1, b_r1, PQ, bits);
        k3_pool<<<B / 8, 256, 0, stream>>>(w_pool, b_pool, bits, out);
    } else {
        unsigned long long* bits = (unsigned long long*)d_ws;
        k2_step<1><<<(B * T) / 4, 256, 0, stream>>>(x, nodes, nbr1, nbr2,
            w_l0, b_l0, w_r0, b_r0, w_l1, b_l1, w_r1, b_r1, nullptr, bits);
        k3_pool<<<B / 8, 256, 0, stream>>>(w_pool, b_pool, bits, out);
    }
}